// Round 4
// baseline (387.019 us; speedup 1.0000x reference)
//
#include <hip/hip_runtime.h>

// ---------- helpers ----------
typedef __attribute__((ext_vector_type(8))) __bf16 bf16x8;
typedef __attribute__((ext_vector_type(4))) float f32x4;

__device__ inline unsigned short f2bf(float f) {
    union { float f; unsigned int i; } v; v.f = f;
    unsigned int i = v.i;
    unsigned int r = i + 0x7FFFu + ((i >> 16) & 1u);   // RNE
    return (unsigned short)(r >> 16);
}
__device__ inline float bf2f(unsigned short u) {
    union { unsigned int i; float f; } v; v.i = ((unsigned int)u) << 16; return v.f;
}

__device__ inline void gload_lds16(const void* g, void* l) {
    __builtin_amdgcn_global_load_lds(
        (const __attribute__((address_space(1))) unsigned int*)g,
        (__attribute__((address_space(3))) unsigned int*)l, 16, 0, 0);
}

// inline-asm LDS read: 32-bit byte offset into dynamic LDS (base 0 — no static
// __shared__ in the gemm kernel). Invisible to the memory legalizer, so no
// compiler-inserted vmcnt(0) against in-flight global_load_lds prefetches.
__device__ inline bf16x8 ldsrd(unsigned off) {
    bf16x8 r;
    asm volatile("ds_read_b128 %0, %1" : "=v"(r) : "v"(off));
    return r;
}

// ---------- kernel 1: cast x (fp32 -> bf16) ----------
__global__ __launch_bounds__(256) void cast_x(const float* __restrict__ x,
                                              unsigned short* __restrict__ xb, int n4) {
    int idx = blockIdx.x * blockDim.x + threadIdx.x;
    int stride = gridDim.x * blockDim.x;
    for (int i = idx; i < n4; i += stride) {
        float4 v = ((const float4*)x)[i];
        ushort4 o;
        o.x = f2bf(v.x); o.y = f2bf(v.y); o.z = f2bf(v.z); o.w = f2bf(v.w);
        ((ushort4*)xb)[i] = o;
    }
}

// ---------- kernel 2: cast W into Wcat rows 0..1023 ----------
__global__ __launch_bounds__(256) void cast_w(const float* __restrict__ W,
                                              unsigned short* __restrict__ wcat) {
    int i = blockIdx.x * 256 + threadIdx.x;
    float4 v = ((const float4*)W)[i];
    ushort4 o;
    o.x = f2bf(v.x); o.y = f2bf(v.y); o.z = f2bf(v.z); o.w = f2bf(v.w);
    ((ushort4*)wcat)[i] = o;
}

// ---------- kernel 3: build M^T into Wcat rows 1024..2047 ----------
__global__ __launch_bounds__(256) void build_m(const float* __restrict__ A,
                                               const float* __restrict__ Bm,
                                               const float* __restrict__ scores,
                                               unsigned short* __restrict__ wcat) {
    int D = blockIdx.x;      // 1024
    int tx = threadIdx.x;    // 256
    float acc[4] = {0.f, 0.f, 0.f, 0.f};
    for (int e = 0; e < 16; ++e) {
        float pe = scores[e];
        float bb[16];
        #pragma unroll
        for (int r = 0; r < 16; ++r) bb[r] = pe * Bm[(size_t)((e << 4) + r) * 1024 + D];
        #pragma unroll
        for (int j = 0; j < 4; ++j) {
            int d = tx + j * 256;
            const float4* ap = (const float4*)(A + (((size_t)e * 1024 + d) << 4));
            float4 a0 = ap[0], a1 = ap[1], a2 = ap[2], a3 = ap[3];
            acc[j] += a0.x*bb[0]  + a0.y*bb[1]  + a0.z*bb[2]  + a0.w*bb[3]
                    + a1.x*bb[4]  + a1.y*bb[5]  + a1.z*bb[6]  + a1.w*bb[7]
                    + a2.x*bb[8]  + a2.y*bb[9]  + a2.z*bb[10] + a2.w*bb[11]
                    + a3.x*bb[12] + a3.y*bb[13] + a3.z*bb[14] + a3.w*bb[15];
        }
    }
    size_t rowbase = (size_t)(1024 + D) * 1024;
    #pragma unroll
    for (int j = 0; j < 4; ++j) wcat[rowbase + tx + j * 256] = f2bf(acc[j]);
}

// ---------- kernel 4: 256x256-tile 8-phase GEMM, asm ds_read ----------
// out2[t][n] = sum_k xb[t][k] * wcat[n][k];  M=32768, N=2048, K=1024.
// BM=BN=256, BK=64, 8 waves (2Mx4N), 128KiB dynamic LDS, double-buffered.
// Chunk-major LDS [4 chunks][256 rows][16B]: conflict-free ds_read_b128 AND
// linear global_load_lds staging. All LDS reads are inline asm; the ONLY
// vmem wait is the counted vmcnt(4) once per K-tile (m218 counted-vmcnt).
__global__ __launch_bounds__(512, 2) void gemm_zm8(const unsigned short* __restrict__ xb,
                                                   const unsigned short* __restrict__ wcat,
                                                   const float* __restrict__ bias,
                                                   float* __restrict__ zout,
                                                   unsigned short* __restrict__ mbuf) {
    extern __shared__ char lds[];
    const int tid = threadIdx.x;
    const int l = tid & 63;
    const int w = tid >> 6;
    const int wr = w >> 2;        // 0..1  (M half)
    const int wc = w & 3;         // 0..3  (N quarter)

    const int bid = blockIdx.x;
    const int swz = (bid & 7) * 128 + (bid >> 3);
    const int brow = (swz >> 3) * 256;    // 128 M-tiles
    const int bcol = (swz & 7) * 256;     // 8 N-tiles

    const unsigned lco = (unsigned)((l >> 4) * 4096 + (l & 15) * 16);
    const unsigned abase0 = lco + (unsigned)(wr * 2048);
    const unsigned bbase0 = 32768u + lco + (unsigned)(wc * 1024);
    const int sr = tid & 255;
    const int sc = tid >> 8;

    f32x4 acc[8][4] = {};

#define STAGE(mat, baserow, T, h, breg) do {                                        \
        int T_ = (T);                                                               \
        int Ts_ = T_ > 15 ? 15 : T_;                                                \
        char* rg_ = lds + ((T_ & 1) * 65536 + (breg) + (h) * 16384);                \
        const unsigned short* g_ = (mat) + (size_t)((baserow) + sr) * 1024          \
                                   + Ts_ * 64 + (h) * 32 + sc * 8;                  \
        gload_lds16(g_,      rg_ + sc * 4096 + sr * 16);                            \
        gload_lds16(g_ + 16, rg_ + (sc + 2) * 4096 + sr * 16);                      \
    } while (0)

#define WAIT_LGKM_SB() do {                                                         \
        asm volatile("s_waitcnt lgkmcnt(0)" ::: "memory");                          \
        __builtin_amdgcn_sched_barrier(0);                                          \
    } while (0)

#define MFMA16(ACCBASE, A0, A1, A2, A3) do {                                        \
        __builtin_amdgcn_s_setprio(1);                                              \
        _Pragma("unroll")                                                           \
        for (int nf = 0; nf < 4; ++nf) {                                            \
            acc[ACCBASE + 0][nf] = __builtin_amdgcn_mfma_f32_16x16x32_bf16(A0, bfr[nf], acc[ACCBASE + 0][nf], 0, 0, 0); \
            acc[ACCBASE + 1][nf] = __builtin_amdgcn_mfma_f32_16x16x32_bf16(A1, bfr[nf], acc[ACCBASE + 1][nf], 0, 0, 0); \
            acc[ACCBASE + 2][nf] = __builtin_amdgcn_mfma_f32_16x16x32_bf16(A2, bfr[nf], acc[ACCBASE + 2][nf], 0, 0, 0); \
            acc[ACCBASE + 3][nf] = __builtin_amdgcn_mfma_f32_16x16x32_bf16(A3, bfr[nf], acc[ACCBASE + 3][nf], 0, 0, 0); \
        }                                                                           \
        __builtin_amdgcn_s_setprio(0);                                              \
    } while (0)

    // ---- prologue: tile0 fully + tile1 k0 halves (6 half-tiles, 12 loads) ----
    STAGE(xb,   brow, 0, 0, 0);
    STAGE(wcat, bcol, 0, 0, 32768);
    STAGE(xb,   brow, 0, 1, 0);
    STAGE(wcat, bcol, 0, 1, 32768);
    STAGE(xb,   brow, 1, 0, 0);
    STAGE(wcat, bcol, 1, 0, 32768);
    asm volatile("s_waitcnt vmcnt(4)" ::: "memory");   // tile0 landed; tile1-k0 in flight
    __builtin_amdgcn_s_barrier();

    for (int t = 0; t < 16; ++t) {
        const unsigned bufo = (unsigned)((t & 1) * 65536);
        bf16x8 afr[4], bfr[4];

        // ---- phase 0: k0, m-frags 0-3 ----
        {
            unsigned ab = bufo + abase0, bb = bufo + bbase0;
            afr[0] = ldsrd(ab);        afr[1] = ldsrd(ab + 256);
            afr[2] = ldsrd(ab + 512);  afr[3] = ldsrd(ab + 768);
            bfr[0] = ldsrd(bb);        bfr[1] = ldsrd(bb + 256);
            bfr[2] = ldsrd(bb + 512);  bfr[3] = ldsrd(bb + 768);
        }
        STAGE(xb, brow, t + 1, 1, 0);               // A-k1(t+1) -> other buf
        __builtin_amdgcn_s_barrier();
        WAIT_LGKM_SB();
        MFMA16(0, afr[0], afr[1], afr[2], afr[3]);
        __builtin_amdgcn_s_barrier();

        // ---- phase 1: k0, m-frags 4-7 (reuse bfr) ----
        {
            unsigned ab = bufo + abase0 + 1024;
            afr[0] = ldsrd(ab);        afr[1] = ldsrd(ab + 256);
            afr[2] = ldsrd(ab + 512);  afr[3] = ldsrd(ab + 768);
        }
        STAGE(wcat, bcol, t + 1, 1, 32768);         // B-k1(t+1) -> other buf
        __builtin_amdgcn_s_barrier();
        WAIT_LGKM_SB();
        MFMA16(4, afr[0], afr[1], afr[2], afr[3]);
        __builtin_amdgcn_s_barrier();

        // ---- phase 2: k1, m-frags 0-3 ----
        {
            unsigned ab = bufo + 16384 + abase0, bb = bufo + 16384 + bbase0;
            afr[0] = ldsrd(ab);        afr[1] = ldsrd(ab + 256);
            afr[2] = ldsrd(ab + 512);  afr[3] = ldsrd(ab + 768);
            bfr[0] = ldsrd(bb);        bfr[1] = ldsrd(bb + 256);
            bfr[2] = ldsrd(bb + 512);  bfr[3] = ldsrd(bb + 768);
        }
        STAGE(xb, brow, t + 2, 0, 0);               // A-k0(t+2) -> this buf (reads done ph1)
        __builtin_amdgcn_s_barrier();
        WAIT_LGKM_SB();
        MFMA16(0, afr[0], afr[1], afr[2], afr[3]);
        __builtin_amdgcn_s_barrier();

        // ---- phase 3: k1, m-frags 4-7 ----
        {
            unsigned ab = bufo + 16384 + abase0 + 1024;
            afr[0] = ldsrd(ab);        afr[1] = ldsrd(ab + 256);
            afr[2] = ldsrd(ab + 512);  afr[3] = ldsrd(ab + 768);
        }
        STAGE(wcat, bcol, t + 2, 0, 32768);         // B-k0(t+2) -> this buf (reads done ph0)
        __builtin_amdgcn_s_barrier();
        WAIT_LGKM_SB();
        MFMA16(4, afr[0], afr[1], afr[2], afr[3]);
        // counted vmcnt: keep newest 4 loads (2 half-tiles) in flight across the barrier
        asm volatile("s_waitcnt vmcnt(4)" ::: "memory");
        __builtin_amdgcn_s_barrier();
    }

    // ---- C-write epilogue: z half fp32 (+bias) -> d_out, m half bf16 -> mbuf ----
    const bool is_z = (bcol < 1024);
    const int crow0 = brow + wr * 128 + (l >> 4) * 4;
    const int ccol0 = bcol + wc * 64 + (l & 15);
    #pragma unroll
    for (int nf = 0; nf < 4; ++nf) {
        int col = ccol0 + nf * 16;
        if (is_z) {
            float bb = bias[col];
            #pragma unroll
            for (int mf = 0; mf < 8; ++mf) {
                int row = crow0 + mf * 16;
                f32x4 v = acc[mf][nf];
                #pragma unroll
                for (int j = 0; j < 4; ++j)
                    zout[(size_t)(row + j) * 1024 + col] = v[j] + bb;
            }
        } else {
            int mc = col - 1024;
            #pragma unroll
            for (int mf = 0; mf < 8; ++mf) {
                int row = crow0 + mf * 16;
                f32x4 v = acc[mf][nf];
                #pragma unroll
                for (int j = 0; j < 4; ++j)
                    mbuf[(size_t)(row + j) * 1024 + mc] = f2bf(v[j]);
            }
        }
    }
#undef STAGE
#undef WAIT_LGKM_SB
#undef MFMA16
}

// ---------- kernel 5: norm-clamp epilogue, rewrites d_out in place ----------
__global__ __launch_bounds__(256) void epilogue(float* __restrict__ out,
                                                const unsigned short* __restrict__ mbuf,
                                                const int* __restrict__ lidx) {
    int row = blockIdx.x;
    int tx = threadIdx.x;
    size_t base = (size_t)row * 1024 + tx * 4;

    float4 z = *(const float4*)&out[base];
    ushort4 mv = *(const ushort4*)&mbuf[base];
    float m0 = bf2f(mv.x), m1 = bf2f(mv.y), m2 = bf2f(mv.z), m3 = bf2f(mv.w);

    float sz = z.x * z.x + z.y * z.y + z.z * z.z + z.w * z.w;
    float sm = m0 * m0 + m1 * m1 + m2 * m2 + m3 * m3;

    #pragma unroll
    for (int off = 32; off > 0; off >>= 1) {
        sz += __shfl_xor(sz, off);
        sm += __shfl_xor(sm, off);
    }
    __shared__ float red[8];
    int wv = tx >> 6;
    if ((tx & 63) == 0) { red[wv * 2] = sz; red[wv * 2 + 1] = sm; }
    __syncthreads();
    sz = red[0] + red[2] + red[4] + red[6];
    sm = red[1] + red[3] + red[5] + red[7];

    float gamma = fminf(0.5f * sqrtf(sz) / (sqrtf(sm) + 1e-6f), 1.0f);
    if (lidx[0] < 0) gamma = 0.f;

    float4 o;
    o.x = z.x + gamma * m0; o.y = z.y + gamma * m1;
    o.z = z.z + gamma * m2; o.w = z.w + gamma * m3;
    *(float4*)&out[base] = o;
}

// ---------- launcher ----------
extern "C" void kernel_launch(void* const* d_in, const int* in_sizes, int n_in,
                              void* d_out, int out_size, void* d_ws, size_t ws_size,
                              hipStream_t stream) {
    const float* x  = (const float*)d_in[0];
    const float* W  = (const float*)d_in[1];
    const float* b  = (const float*)d_in[2];
    const float* A  = (const float*)d_in[3];
    const float* Bm = (const float*)d_in[4];
    const float* sc = (const float*)d_in[5];
    const int* lidx = (const int*)d_in[6];
    float* out = (float*)d_out;

    // ws layout (bytes): xb 64MB | wcat 4MB | mbuf 64MB  (132MB total)
    unsigned short* xb   = (unsigned short*)d_ws;
    unsigned short* wcat = (unsigned short*)((char*)d_ws + 67108864);
    unsigned short* mbuf = (unsigned short*)((char*)d_ws + 71303168);

    hipFuncSetAttribute((const void*)gemm_zm8,
                        hipFuncAttributeMaxDynamicSharedMemorySize, 131072);

    cast_x<<<2048, 256, 0, stream>>>(x, xb, 33554432 / 4);
    cast_w<<<1024, 256, 0, stream>>>(W, wcat);
    build_m<<<1024, 256, 0, stream>>>(A, Bm, sc, wcat);
    gemm_zm8<<<1024, 512, 131072, stream>>>(xb, wcat, b, out, mbuf);
    epilogue<<<32768, 256, 0, stream>>>(out, mbuf, lidx);
}

// Round 5
// 308.088 us; speedup vs baseline: 1.2562x; 1.2562x over previous
//
#include <hip/hip_runtime.h>

// ---------- helpers ----------
typedef __attribute__((ext_vector_type(8))) __bf16 bf16x8;
typedef __attribute__((ext_vector_type(4))) float f32x4;

__device__ inline unsigned short f2bf(float f) {
    union { float f; unsigned int i; } v; v.f = f;
    unsigned int i = v.i;
    unsigned int r = i + 0x7FFFu + ((i >> 16) & 1u);   // RNE
    return (unsigned short)(r >> 16);
}
__device__ inline float bf2f(unsigned short u) {
    union { unsigned int i; float f; } v; v.i = ((unsigned int)u) << 16; return v.f;
}

__device__ inline void gload_lds16(const void* g, void* l) {
    __builtin_amdgcn_global_load_lds(
        (const __attribute__((address_space(1))) unsigned int*)g,
        (__attribute__((address_space(3))) unsigned int*)l, 16, 0, 0);
}

// inline-asm LDS read (32-bit byte offset, dynamic-LDS base 0); invisible to
// the memory legalizer -> no compiler vmcnt(0) drains against LDS-DMA.
__device__ inline bf16x8 ldsrd(unsigned off) {
    bf16x8 r;
    asm volatile("ds_read_b128 %0, %1" : "=v"(r) : "v"(off));
    return r;
}

// ---------- kernel 1: cast x (fp32 -> bf16) ----------
__global__ __launch_bounds__(256) void cast_x(const float* __restrict__ x,
                                              unsigned short* __restrict__ xb, int n4) {
    int idx = blockIdx.x * blockDim.x + threadIdx.x;
    int stride = gridDim.x * blockDim.x;
    for (int i = idx; i < n4; i += stride) {
        float4 v = ((const float4*)x)[i];
        ushort4 o;
        o.x = f2bf(v.x); o.y = f2bf(v.y); o.z = f2bf(v.z); o.w = f2bf(v.w);
        ((ushort4*)xb)[i] = o;
    }
}

// ---------- kernel 2: cast W into Wcat rows 0..1023 ----------
__global__ __launch_bounds__(256) void cast_w(const float* __restrict__ W,
                                              unsigned short* __restrict__ wcat) {
    int i = blockIdx.x * 256 + threadIdx.x;
    float4 v = ((const float4*)W)[i];
    ushort4 o;
    o.x = f2bf(v.x); o.y = f2bf(v.y); o.z = f2bf(v.z); o.w = f2bf(v.w);
    ((ushort4*)wcat)[i] = o;
}

// ---------- kernel 3: build M^T into Wcat rows 1024..2047 ----------
__global__ __launch_bounds__(256) void build_m(const float* __restrict__ A,
                                               const float* __restrict__ Bm,
                                               const float* __restrict__ scores,
                                               unsigned short* __restrict__ wcat) {
    int D = blockIdx.x;      // 1024
    int tx = threadIdx.x;    // 256
    float acc[4] = {0.f, 0.f, 0.f, 0.f};
    for (int e = 0; e < 16; ++e) {
        float pe = scores[e];
        float bb[16];
        #pragma unroll
        for (int r = 0; r < 16; ++r) bb[r] = pe * Bm[(size_t)((e << 4) + r) * 1024 + D];
        #pragma unroll
        for (int j = 0; j < 4; ++j) {
            int d = tx + j * 256;
            const float4* ap = (const float4*)(A + (((size_t)e * 1024 + d) << 4));
            float4 a0 = ap[0], a1 = ap[1], a2 = ap[2], a3 = ap[3];
            acc[j] += a0.x*bb[0]  + a0.y*bb[1]  + a0.z*bb[2]  + a0.w*bb[3]
                    + a1.x*bb[4]  + a1.y*bb[5]  + a1.z*bb[6]  + a1.w*bb[7]
                    + a2.x*bb[8]  + a2.y*bb[9]  + a2.z*bb[10] + a2.w*bb[11]
                    + a3.x*bb[12] + a3.y*bb[13] + a3.z*bb[14] + a3.w*bb[15];
        }
    }
    size_t rowbase = (size_t)(1024 + D) * 1024;
    #pragma unroll
    for (int j = 0; j < 4; ++j) wcat[rowbase + tx + j * 256] = f2bf(acc[j]);
}

// ---------- kernel 4: 256x256-tile 4-phase GEMM, coalesced staging + T2 swizzle ----------
// out2[t][n] = sum_k xb[t][k] * wcat[n][k];  M=32768, N=2048, K=1024.
// BM=BN=256, BK=64, 8 waves (2Mx4N), 128KiB dynamic LDS, double-buffered.
// LDS per buf (64KB): A [256 rows][64 k] @0, B same @32768; 128B rows.
// XOR swizzle: physical 16B-chunk = logical_chunk ^ (row&7); applied on the
// GLOBAL source of global_load_lds (permutation stays inside one 128B line ->
// coalesced, 8 L2 reqs/instr) and on the ds_read offsets (banks 8-way spread).
__global__ __launch_bounds__(512, 2) void gemm_zm8(const unsigned short* __restrict__ xb,
                                                   const unsigned short* __restrict__ wcat,
                                                   const float* __restrict__ bias,
                                                   float* __restrict__ zout,
                                                   unsigned short* __restrict__ mbuf) {
    extern __shared__ char lds[];
    const int tid = threadIdx.x;
    const int l = tid & 63;
    const int w = tid >> 6;
    const int wr = w >> 2;        // 0..1  (M: rows wr*64+[0,64) and 128+wr*64+[0,64))
    const int wc = w & 3;         // 0..3  (N quarter)

    const int bid = blockIdx.x;
    const int swz = (bid & 7) * 128 + (bid >> 3);
    const int brow = (swz >> 3) * 256;    // 128 M-tiles
    const int bcol = (swz & 7) * 256;     // 8 N-tiles

    // per-lane ds_read bases: row = <waverow> + (l&15); chunk xor key = l&7
    const unsigned rA128 = (unsigned)((wr * 64 + (l & 15)) * 128);
    const unsigned rB128 = 32768u + (unsigned)((wc * 64 + (l & 15)) * 128);
    const unsigned pck0 = (((l >> 4)) ^ (l & 7)) * 16u;        // ks0 chunk byte
    const unsigned pck1 = ((4 + (l >> 4)) ^ (l & 7)) * 16u;    // ks1 chunk byte

    // staging: thread ti covers rows h*128 + ti/8 (+64), permuted chunk ti%8
    const unsigned strow = (unsigned)(tid >> 3);               // 0..63
    const unsigned stchunk = (unsigned)((tid & 7) ^ (strow & 7)); // src logical chunk
    const unsigned stlds = (unsigned)(tid * 16);

    f32x4 acc[8][4] = {};

#define STAGE(mat, baserow, T, h, bofs) do {                                        \
        int T_ = (T); int Ts_ = T_ > 15 ? 15 : T_;                                  \
        unsigned db_ = (unsigned)((T_ & 1) * 65536) + (bofs) + (h) * 16384u;        \
        const unsigned short* g_ = (mat) + (size_t)((baserow) + (h) * 128 + strow) * 1024 \
                                   + Ts_ * 64 + stchunk * 8;                        \
        gload_lds16(g_,           lds + db_ + stlds);                               \
        gload_lds16(g_ + 64*1024, lds + db_ + 8192 + stlds);                        \
    } while (0)
    // note: +64 rows in global = +64*1024 elems; (row+64)&7 == row&7 so same chunk perm

#define WAIT_LGKM_SB() do {                                                         \
        asm volatile("s_waitcnt lgkmcnt(0)" ::: "memory");                          \
        __builtin_amdgcn_sched_barrier(0);                                          \
    } while (0)

#define RD_A4(dst, bufo, MBASE, PCK) do {                                           \
        dst[0] = ldsrd((bufo) + rA128 + ((MBASE + 0) & 3) * 2048 + ((MBASE + 0) >> 2) * 16384 + (PCK)); \
        dst[1] = ldsrd((bufo) + rA128 + ((MBASE + 1) & 3) * 2048 + ((MBASE + 1) >> 2) * 16384 + (PCK)); \
        dst[2] = ldsrd((bufo) + rA128 + ((MBASE + 2) & 3) * 2048 + ((MBASE + 2) >> 2) * 16384 + (PCK)); \
        dst[3] = ldsrd((bufo) + rA128 + ((MBASE + 3) & 3) * 2048 + ((MBASE + 3) >> 2) * 16384 + (PCK)); \
    } while (0)

#define RD_B4(dst, bufo, PCK) do {                                                  \
        dst[0] = ldsrd((bufo) + rB128 + 0 * 2048 + (PCK));                          \
        dst[1] = ldsrd((bufo) + rB128 + 1 * 2048 + (PCK));                          \
        dst[2] = ldsrd((bufo) + rB128 + 2 * 2048 + (PCK));                          \
        dst[3] = ldsrd((bufo) + rB128 + 3 * 2048 + (PCK));                          \
    } while (0)

#define MFMA16(ABASE, AFR, BFR) do {                                                \
        __builtin_amdgcn_s_setprio(1);                                              \
        _Pragma("unroll")                                                           \
        for (int nf = 0; nf < 4; ++nf) {                                            \
            acc[ABASE + 0][nf] = __builtin_amdgcn_mfma_f32_16x16x32_bf16(AFR[0], BFR[nf], acc[ABASE + 0][nf], 0, 0, 0); \
            acc[ABASE + 1][nf] = __builtin_amdgcn_mfma_f32_16x16x32_bf16(AFR[1], BFR[nf], acc[ABASE + 1][nf], 0, 0, 0); \
            acc[ABASE + 2][nf] = __builtin_amdgcn_mfma_f32_16x16x32_bf16(AFR[2], BFR[nf], acc[ABASE + 2][nf], 0, 0, 0); \
            acc[ABASE + 3][nf] = __builtin_amdgcn_mfma_f32_16x16x32_bf16(AFR[3], BFR[nf], acc[ABASE + 3][nf], 0, 0, 0); \
        }                                                                           \
        __builtin_amdgcn_s_setprio(0);                                              \
    } while (0)

    // ---- prologue: tile0 all 4 units, then tile1 Bh0+Ah0 (12 loads) ----
    STAGE(xb,   brow, 0, 0, 0u);        // Ah0(0)
    STAGE(wcat, bcol, 0, 0, 32768u);    // Bh0(0)
    STAGE(xb,   brow, 0, 1, 0u);        // Ah1(0)
    STAGE(wcat, bcol, 0, 1, 32768u);    // Bh1(0)
    STAGE(wcat, bcol, 1, 0, 32768u);    // Bh0(1)
    STAGE(xb,   brow, 1, 0, 0u);        // Ah0(1)
    asm volatile("s_waitcnt vmcnt(4)" ::: "memory");   // tile0 landed; tile1 partial in flight
    __builtin_amdgcn_s_barrier();

    for (int t = 0; t < 16; ++t) {
        const unsigned bufo = (unsigned)((t & 1) * 65536);
        bf16x8 afr[4], bfr0[4], bfr1[4];

        // ---- phase 0: ks0 x mf0-3 ----
        RD_A4(afr, bufo, 0, pck0);
        RD_B4(bfr0, bufo, pck0);
        STAGE(xb, brow, t + 1, 1, 0u);              // A-h1(t+1) -> other buf (last read t-1 ph3)
        __builtin_amdgcn_s_barrier();
        WAIT_LGKM_SB();
        MFMA16(0, afr, bfr0);
        __builtin_amdgcn_s_barrier();

        // ---- phase 1: ks0 x mf4-7 (+ prefetch B ks1) ----
        RD_A4(afr, bufo, 4, pck0);
        RD_B4(bfr1, bufo, pck1);
        STAGE(wcat, bcol, t + 1, 1, 32768u);        // B-h1(t+1) -> other buf (last read t-1 ph1)
        __builtin_amdgcn_s_barrier();
        WAIT_LGKM_SB();
        MFMA16(4, afr, bfr0);
        __builtin_amdgcn_s_barrier();

        // ---- phase 2: ks1 x mf0-3 ----
        RD_A4(afr, bufo, 0, pck1);
        STAGE(wcat, bcol, t + 2, 0, 32768u);        // B-h0(t+2) -> this buf (B reads done ph1)
        __builtin_amdgcn_s_barrier();
        WAIT_LGKM_SB();
        MFMA16(0, afr, bfr1);
        __builtin_amdgcn_s_barrier();

        // ---- phase 3: ks1 x mf4-7 ----
        RD_A4(afr, bufo, 4, pck1);
        STAGE(xb, brow, t + 2, 0, 0u);              // A-h0(t+2) -> this buf (A-h0 reads done ph2)
        __builtin_amdgcn_s_barrier();
        WAIT_LGKM_SB();
        MFMA16(4, afr, bfr1);
        // counted vmcnt: keep newest 4 loads (ph2+ph3 stages, for t+2) in flight
        asm volatile("s_waitcnt vmcnt(4)" ::: "memory");
        __builtin_amdgcn_s_barrier();
    }

    // drain LDS-DMA before LDS is handed to the next block
    asm volatile("s_waitcnt vmcnt(0)" ::: "memory");

    // ---- C-write: z half fp32 (+bias) -> d_out, m half bf16 -> mbuf ----
    // row(mf) = wr*64 + (mf&3)*16 + (mf>>2)*128
    const bool is_z = (bcol < 1024);
    const int crow0 = brow + wr * 64 + (l >> 4) * 4;
    const int ccol0 = bcol + wc * 64 + (l & 15);
    #pragma unroll
    for (int nf = 0; nf < 4; ++nf) {
        int col = ccol0 + nf * 16;
        if (is_z) {
            float bb = bias[col];
            #pragma unroll
            for (int mf = 0; mf < 8; ++mf) {
                int row = crow0 + (mf & 3) * 16 + (mf >> 2) * 128;
                f32x4 v = acc[mf][nf];
                #pragma unroll
                for (int j = 0; j < 4; ++j)
                    zout[(size_t)(row + j) * 1024 + col] = v[j] + bb;
            }
        } else {
            int mc = col - 1024;
            #pragma unroll
            for (int mf = 0; mf < 8; ++mf) {
                int row = crow0 + (mf & 3) * 16 + (mf >> 2) * 128;
                f32x4 v = acc[mf][nf];
                #pragma unroll
                for (int j = 0; j < 4; ++j)
                    mbuf[(size_t)(row + j) * 1024 + mc] = f2bf(v[j]);
            }
        }
    }
#undef STAGE
#undef WAIT_LGKM_SB
#undef RD_A4
#undef RD_B4
#undef MFMA16
}

// ---------- kernel 5: norm-clamp epilogue, rewrites d_out in place ----------
__global__ __launch_bounds__(256) void epilogue(float* __restrict__ out,
                                                const unsigned short* __restrict__ mbuf,
                                                const int* __restrict__ lidx) {
    int row = blockIdx.x;
    int tx = threadIdx.x;
    size_t base = (size_t)row * 1024 + tx * 4;

    float4 z = *(const float4*)&out[base];
    ushort4 mv = *(const ushort4*)&mbuf[base];
    float m0 = bf2f(mv.x), m1 = bf2f(mv.y), m2 = bf2f(mv.z), m3 = bf2f(mv.w);

    float sz = z.x * z.x + z.y * z.y + z.z * z.z + z.w * z.w;
    float sm = m0 * m0 + m1 * m1 + m2 * m2 + m3 * m3;

    #pragma unroll
    for (int off = 32; off > 0; off >>= 1) {
        sz += __shfl_xor(sz, off);
        sm += __shfl_xor(sm, off);
    }
    __shared__ float red[8];
    int wv = tx >> 6;
    if ((tx & 63) == 0) { red[wv * 2] = sz; red[wv * 2 + 1] = sm; }
    __syncthreads();
    sz = red[0] + red[2] + red[4] + red[6];
    sm = red[1] + red[3] + red[5] + red[7];

    float gamma = fminf(0.5f * sqrtf(sz) / (sqrtf(sm) + 1e-6f), 1.0f);
    if (lidx[0] < 0) gamma = 0.f;

    float4 o;
    o.x = z.x + gamma * m0; o.y = z.y + gamma * m1;
    o.z = z.z + gamma * m2; o.w = z.w + gamma * m3;
    *(float4*)&out[base] = o;
}

// ---------- launcher ----------
extern "C" void kernel_launch(void* const* d_in, const int* in_sizes, int n_in,
                              void* d_out, int out_size, void* d_ws, size_t ws_size,
                              hipStream_t stream) {
    const float* x  = (const float*)d_in[0];
    const float* W  = (const float*)d_in[1];
    const float* b  = (const float*)d_in[2];
    const float* A  = (const float*)d_in[3];
    const float* Bm = (const float*)d_in[4];
    const float* sc = (const float*)d_in[5];
    const int* lidx = (const int*)d_in[6];
    float* out = (float*)d_out;

    // ws layout (bytes): xb 64MB | wcat 4MB | mbuf 64MB  (132MB total)
    unsigned short* xb   = (unsigned short*)d_ws;
    unsigned short* wcat = (unsigned short*)((char*)d_ws + 67108864);
    unsigned short* mbuf = (unsigned short*)((char*)d_ws + 71303168);

    hipFuncSetAttribute((const void*)gemm_zm8,
                        hipFuncAttributeMaxDynamicSharedMemorySize, 131072);

    cast_x<<<2048, 256, 0, stream>>>(x, xb, 33554432 / 4);
    cast_w<<<1024, 256, 0, stream>>>(W, wcat);
    build_m<<<1024, 256, 0, stream>>>(A, Bm, sc, wcat);
    gemm_zm8<<<1024, 512, 131072, stream>>>(xb, wcat, b, out, mbuf);
    epilogue<<<32768, 256, 0, stream>>>(out, mbuf, lidx);
}

// Round 6
// 275.079 us; speedup vs baseline: 1.4069x; 1.1200x over previous
//
#include <hip/hip_runtime.h>

// ---------- helpers ----------
typedef __attribute__((ext_vector_type(8))) __bf16 bf16x8;
typedef __attribute__((ext_vector_type(8))) unsigned short u16x8;
typedef __attribute__((ext_vector_type(4))) float f32x4;

__device__ inline unsigned short f2bf(float f) {
    union { float f; unsigned int i; } v; v.f = f;
    unsigned int i = v.i;
    unsigned int r = i + 0x7FFFu + ((i >> 16) & 1u);   // RNE
    return (unsigned short)(r >> 16);
}
__device__ inline float bf2f(unsigned short u) {
    union { unsigned int i; float f; } v; v.i = ((unsigned int)u) << 16; return v.f;
}

__device__ inline void gload_lds16(const void* g, void* l) {
    __builtin_amdgcn_global_load_lds(
        (const __attribute__((address_space(1))) unsigned int*)g,
        (__attribute__((address_space(3))) unsigned int*)l, 16, 0, 0);
}

// inline-asm LDS read (32-bit byte offset, dynamic-LDS base 0); invisible to
// the memory legalizer -> no compiler vmcnt(0) drains against LDS-DMA.
__device__ inline bf16x8 ldsrd(unsigned off) {
    bf16x8 r;
    asm volatile("ds_read_b128 %0, %1" : "=v"(r) : "v"(off));
    return r;
}

// ---------- kernel 1: cast x (fp32 -> bf16) ----------
__global__ __launch_bounds__(256) void cast_x(const float* __restrict__ x,
                                              unsigned short* __restrict__ xb, int n4) {
    int idx = blockIdx.x * blockDim.x + threadIdx.x;
    int stride = gridDim.x * blockDim.x;
    for (int i = idx; i < n4; i += stride) {
        float4 v = ((const float4*)x)[i];
        ushort4 o;
        o.x = f2bf(v.x); o.y = f2bf(v.y); o.z = f2bf(v.z); o.w = f2bf(v.w);
        ((ushort4*)xb)[i] = o;
    }
}

// ---------- kernel 2: cast W into Wcat rows 0..1023 ----------
__global__ __launch_bounds__(256) void cast_w(const float* __restrict__ W,
                                              unsigned short* __restrict__ wcat) {
    int i = blockIdx.x * 256 + threadIdx.x;
    float4 v = ((const float4*)W)[i];
    ushort4 o;
    o.x = f2bf(v.x); o.y = f2bf(v.y); o.z = f2bf(v.z); o.w = f2bf(v.w);
    ((ushort4*)wcat)[i] = o;
}

// ---------- kernel 3: build M^T into Wcat rows 1024..2047 ----------
__global__ __launch_bounds__(256) void build_m(const float* __restrict__ A,
                                               const float* __restrict__ Bm,
                                               const float* __restrict__ scores,
                                               unsigned short* __restrict__ wcat) {
    int D = blockIdx.x;      // 1024
    int tx = threadIdx.x;    // 256
    float acc[4] = {0.f, 0.f, 0.f, 0.f};
    for (int e = 0; e < 16; ++e) {
        float pe = scores[e];
        float bb[16];
        #pragma unroll
        for (int r = 0; r < 16; ++r) bb[r] = pe * Bm[(size_t)((e << 4) + r) * 1024 + D];
        #pragma unroll
        for (int j = 0; j < 4; ++j) {
            int d = tx + j * 256;
            const float4* ap = (const float4*)(A + (((size_t)e * 1024 + d) << 4));
            float4 a0 = ap[0], a1 = ap[1], a2 = ap[2], a3 = ap[3];
            acc[j] += a0.x*bb[0]  + a0.y*bb[1]  + a0.z*bb[2]  + a0.w*bb[3]
                    + a1.x*bb[4]  + a1.y*bb[5]  + a1.z*bb[6]  + a1.w*bb[7]
                    + a2.x*bb[8]  + a2.y*bb[9]  + a2.z*bb[10] + a2.w*bb[11]
                    + a3.x*bb[12] + a3.y*bb[13] + a3.z*bb[14] + a3.w*bb[15];
        }
    }
    size_t rowbase = (size_t)(1024 + D) * 1024;
    #pragma unroll
    for (int j = 0; j < 4; ++j) wcat[rowbase + tx + j * 256] = f2bf(acc[j]);
}

// ---------- kernel 4: 256x256-tile 4-phase GEMM ----------
// out2[t][n] = sum_k xb[t][k] * wcat[n][k];  M=32768, N=2048, K=1024.
// BM=BN=256, BK=64, 8 waves (2Mx4N), 128KiB dynamic LDS, double-buffered.
// Coalesced swizzled staging (R5). NEW: C-write via LDS transpose -> d_out
// packed bf16 rows [1024 z | 1024 m] (4KB = the fp32 row footprint), fully
// coalesced 512B runs, no extra workspace.
__global__ __launch_bounds__(512, 2) void gemm_zm8(const unsigned short* __restrict__ xb,
                                                   const unsigned short* __restrict__ wcat,
                                                   const float* __restrict__ bias,
                                                   float* __restrict__ zout) {
    extern __shared__ char lds[];
    const int tid = threadIdx.x;
    const int l = tid & 63;
    const int w = tid >> 6;
    const int wr = w >> 2;        // 0..1
    const int wc = w & 3;         // 0..3

    const int bid = blockIdx.x;
    const int swz = (bid & 7) * 128 + (bid >> 3);
    const int brow = (swz >> 3) * 256;    // 128 M-tiles
    const int bcol = (swz & 7) * 256;     // 8 N-tiles

    // per-lane ds_read bases: row = <waverow> + (l&15); chunk xor key = l&7
    const unsigned rA128 = (unsigned)((wr * 64 + (l & 15)) * 128);
    const unsigned rB128 = 32768u + (unsigned)((wc * 64 + (l & 15)) * 128);
    const unsigned pck0 = (((l >> 4)) ^ (l & 7)) * 16u;        // ks0 chunk byte
    const unsigned pck1 = ((4 + (l >> 4)) ^ (l & 7)) * 16u;    // ks1 chunk byte

    // staging: thread ti covers rows h*128 + ti/8 (+64), permuted chunk ti%8
    const unsigned strow = (unsigned)(tid >> 3);               // 0..63
    const unsigned stchunk = (unsigned)((tid & 7) ^ (strow & 7));
    const unsigned stlds = (unsigned)(tid * 16);

    f32x4 acc[8][4] = {};

#define STAGE(mat, baserow, T, h, bofs) do {                                        \
        int T_ = (T); int Ts_ = T_ > 15 ? 15 : T_;                                  \
        unsigned db_ = (unsigned)((T_ & 1) * 65536) + (bofs) + (h) * 16384u;        \
        const unsigned short* g_ = (mat) + (size_t)((baserow) + (h) * 128 + strow) * 1024 \
                                   + Ts_ * 64 + stchunk * 8;                        \
        gload_lds16(g_,           lds + db_ + stlds);                               \
        gload_lds16(g_ + 64*1024, lds + db_ + 8192 + stlds);                        \
    } while (0)

#define WAIT_LGKM_SB() do {                                                         \
        asm volatile("s_waitcnt lgkmcnt(0)" ::: "memory");                          \
        __builtin_amdgcn_sched_barrier(0);                                          \
    } while (0)

#define RD_A4(dst, bufo, MBASE, PCK) do {                                           \
        dst[0] = ldsrd((bufo) + rA128 + ((MBASE + 0) & 3) * 2048 + ((MBASE + 0) >> 2) * 16384 + (PCK)); \
        dst[1] = ldsrd((bufo) + rA128 + ((MBASE + 1) & 3) * 2048 + ((MBASE + 1) >> 2) * 16384 + (PCK)); \
        dst[2] = ldsrd((bufo) + rA128 + ((MBASE + 2) & 3) * 2048 + ((MBASE + 2) >> 2) * 16384 + (PCK)); \
        dst[3] = ldsrd((bufo) + rA128 + ((MBASE + 3) & 3) * 2048 + ((MBASE + 3) >> 2) * 16384 + (PCK)); \
    } while (0)

#define RD_B4(dst, bufo, PCK) do {                                                  \
        dst[0] = ldsrd((bufo) + rB128 + 0 * 2048 + (PCK));                          \
        dst[1] = ldsrd((bufo) + rB128 + 1 * 2048 + (PCK));                          \
        dst[2] = ldsrd((bufo) + rB128 + 2 * 2048 + (PCK));                          \
        dst[3] = ldsrd((bufo) + rB128 + 3 * 2048 + (PCK));                          \
    } while (0)

#define MFMA16(ABASE, AFR, BFR) do {                                                \
        __builtin_amdgcn_s_setprio(1);                                              \
        _Pragma("unroll")                                                           \
        for (int nf = 0; nf < 4; ++nf) {                                            \
            acc[ABASE + 0][nf] = __builtin_amdgcn_mfma_f32_16x16x32_bf16(AFR[0], BFR[nf], acc[ABASE + 0][nf], 0, 0, 0); \
            acc[ABASE + 1][nf] = __builtin_amdgcn_mfma_f32_16x16x32_bf16(AFR[1], BFR[nf], acc[ABASE + 1][nf], 0, 0, 0); \
            acc[ABASE + 2][nf] = __builtin_amdgcn_mfma_f32_16x16x32_bf16(AFR[2], BFR[nf], acc[ABASE + 2][nf], 0, 0, 0); \
            acc[ABASE + 3][nf] = __builtin_amdgcn_mfma_f32_16x16x32_bf16(AFR[3], BFR[nf], acc[ABASE + 3][nf], 0, 0, 0); \
        }                                                                           \
        __builtin_amdgcn_s_setprio(0);                                              \
    } while (0)

    // ---- prologue ----
    STAGE(xb,   brow, 0, 0, 0u);
    STAGE(wcat, bcol, 0, 0, 32768u);
    STAGE(xb,   brow, 0, 1, 0u);
    STAGE(wcat, bcol, 0, 1, 32768u);
    STAGE(wcat, bcol, 1, 0, 32768u);
    STAGE(xb,   brow, 1, 0, 0u);
    asm volatile("s_waitcnt vmcnt(4)" ::: "memory");
    __builtin_amdgcn_s_barrier();

    for (int t = 0; t < 16; ++t) {
        const unsigned bufo = (unsigned)((t & 1) * 65536);
        bf16x8 afr[4], bfr0[4], bfr1[4];

        // ---- phase 0: ks0 x mf0-3 ----
        RD_A4(afr, bufo, 0, pck0);
        RD_B4(bfr0, bufo, pck0);
        STAGE(xb, brow, t + 1, 1, 0u);
        __builtin_amdgcn_s_barrier();
        WAIT_LGKM_SB();
        MFMA16(0, afr, bfr0);
        __builtin_amdgcn_s_barrier();

        // ---- phase 1: ks0 x mf4-7 (+ prefetch B ks1) ----
        RD_A4(afr, bufo, 4, pck0);
        RD_B4(bfr1, bufo, pck1);
        STAGE(wcat, bcol, t + 1, 1, 32768u);
        __builtin_amdgcn_s_barrier();
        WAIT_LGKM_SB();
        MFMA16(4, afr, bfr0);
        __builtin_amdgcn_s_barrier();

        // ---- phase 2: ks1 x mf0-3 ----
        RD_A4(afr, bufo, 0, pck1);
        STAGE(wcat, bcol, t + 2, 0, 32768u);
        __builtin_amdgcn_s_barrier();
        WAIT_LGKM_SB();
        MFMA16(0, afr, bfr1);
        __builtin_amdgcn_s_barrier();

        // ---- phase 3: ks1 x mf4-7 ----
        RD_A4(afr, bufo, 4, pck1);
        STAGE(xb, brow, t + 2, 0, 0u);
        __builtin_amdgcn_s_barrier();
        WAIT_LGKM_SB();
        MFMA16(4, afr, bfr1);
        asm volatile("s_waitcnt vmcnt(4)" ::: "memory");
        __builtin_amdgcn_s_barrier();
    }

    // drain all LDS-DMA before reusing LDS as the C-transpose buffer
    asm volatile("s_waitcnt vmcnt(0)" ::: "memory");
    __builtin_amdgcn_s_barrier();

    // ---- C-write: scatter acc -> LDS [256][256] bf16, then coalesced out ----
    unsigned short* tlds = (unsigned short*)lds;
    const bool is_z = (bcol < 1024);
    {
        const int crow = wr * 64 + (l >> 4) * 4;
        const int ccol = wc * 64 + (l & 15);
        #pragma unroll
        for (int nf = 0; nf < 4; ++nf) {
            int col = ccol + nf * 16;
            float bb = is_z ? bias[bcol + col] : 0.f;
            #pragma unroll
            for (int mf = 0; mf < 8; ++mf) {
                int row = crow + (mf & 3) * 16 + (mf >> 2) * 128;
                f32x4 v = acc[mf][nf];
                #pragma unroll
                for (int j = 0; j < 4; ++j)
                    tlds[(row + j) * 256 + col] = f2bf(v[j] + bb);
            }
        }
    }
    __syncthreads();
    {
        // d_out as packed bf16: row r = [1024 z | 1024 m] (u16 units, 2048/row)
        unsigned short* og = (unsigned short*)zout;
        const int rr = tid >> 5;           // 0..15
        const int c16 = (tid & 31) * 8;    // u16 col within 256
        #pragma unroll
        for (int p = 0; p < 16; ++p) {
            int row = p * 16 + rr;
            u16x8 v = *(const u16x8*)&tlds[row * 256 + c16];
            *(u16x8*)&og[(size_t)(brow + row) * 2048 + bcol + c16] = v;
        }
    }
#undef STAGE
#undef WAIT_LGKM_SB
#undef RD_A4
#undef RD_B4
#undef MFMA16
}

// ---------- kernel 5: in-place norm-clamp epilogue ----------
// d_out row r arrives as packed bf16 [1024 z | 1024 m]; leaves as 1024 fp32.
__global__ __launch_bounds__(256) void epilogue_ip(float* out, const int* __restrict__ lidx) {
    int row = blockIdx.x;            // 32768
    int tx = threadIdx.x;            // 256
    const unsigned short* io = (const unsigned short*)out;
    size_t base = (size_t)row * 2048;

    ushort4 zv = *(const ushort4*)&io[base + tx * 4];
    ushort4 mv = *(const ushort4*)&io[base + 1024 + tx * 4];
    float z0 = bf2f(zv.x), z1 = bf2f(zv.y), z2 = bf2f(zv.z), z3 = bf2f(zv.w);
    float m0 = bf2f(mv.x), m1 = bf2f(mv.y), m2 = bf2f(mv.z), m3 = bf2f(mv.w);

    float sz = z0 * z0 + z1 * z1 + z2 * z2 + z3 * z3;
    float sm = m0 * m0 + m1 * m1 + m2 * m2 + m3 * m3;

    #pragma unroll
    for (int off = 32; off > 0; off >>= 1) {
        sz += __shfl_xor(sz, off);
        sm += __shfl_xor(sm, off);
    }
    __shared__ float red[8];
    int wv = tx >> 6;
    if ((tx & 63) == 0) { red[wv * 2] = sz; red[wv * 2 + 1] = sm; }
    __syncthreads();   // also orders: ALL row reads complete before ANY writes
    sz = red[0] + red[2] + red[4] + red[6];
    sm = red[1] + red[3] + red[5] + red[7];

    float gamma = fminf(0.5f * sqrtf(sz) / (sqrtf(sm) + 1e-6f), 1.0f);
    if (lidx[0] < 0) gamma = 0.f;

    float4 o;
    o.x = z0 + gamma * m0; o.y = z1 + gamma * m1;
    o.z = z2 + gamma * m2; o.w = z3 + gamma * m3;
    *(float4*)&out[(size_t)row * 1024 + tx * 4] = o;
}

// ---------- launcher ----------
extern "C" void kernel_launch(void* const* d_in, const int* in_sizes, int n_in,
                              void* d_out, int out_size, void* d_ws, size_t ws_size,
                              hipStream_t stream) {
    const float* x  = (const float*)d_in[0];
    const float* W  = (const float*)d_in[1];
    const float* b  = (const float*)d_in[2];
    const float* A  = (const float*)d_in[3];
    const float* Bm = (const float*)d_in[4];
    const float* sc = (const float*)d_in[5];
    const int* lidx = (const int*)d_in[6];
    float* out = (float*)d_out;

    // ws layout (bytes): xb 64MB | wcat 4MB   (68MB total)
    unsigned short* xb   = (unsigned short*)d_ws;
    unsigned short* wcat = (unsigned short*)((char*)d_ws + 67108864);

    hipFuncSetAttribute((const void*)gemm_zm8,
                        hipFuncAttributeMaxDynamicSharedMemorySize, 131072);

    cast_x<<<2048, 256, 0, stream>>>(x, xb, 33554432 / 4);
    cast_w<<<1024, 256, 0, stream>>>(W, wcat);
    build_m<<<1024, 256, 0, stream>>>(A, Bm, sc, wcat);
    gemm_zm8<<<1024, 512, 131072, stream>>>(xb, wcat, b, out);
    epilogue_ip<<<32768, 256, 0, stream>>>(out, lidx);
}